// Round 9
// baseline (228.103 us; speedup 1.0000x reference)
//
#include <hip/hip_runtime.h>
#include <hip/hip_bf16.h>
#include <stdint.h>

// Problem constants: B=4, S=1024, E=512, H=8, D=64
#define S_LEN 1024
#define E_DIM 512
#define H_NUM 8
#define D_DIM 64
#define B_NUM 4
#define BH_NUM 32

using s16x8 = __attribute__((ext_vector_type(8))) short;           // 8 bf16 (4 VGPRs)
using f32x4 = __attribute__((ext_vector_type(4))) float;           // MFMA accumulator
using us4   = __attribute__((ext_vector_type(4))) unsigned short;  // 4 bf16 (8 B)

typedef const __attribute__((address_space(1))) uint32_t gas_uint;
typedef __attribute__((address_space(3))) uint32_t las_uint;

static __device__ __forceinline__ unsigned short f2bf(float f) {
  __hip_bfloat16 h = __float2bfloat16(f);
  return __builtin_bit_cast(unsigned short, h);
}
static __device__ __forceinline__ float bf2f(unsigned short u) {
  return __bfloat162float(__builtin_bit_cast(__hip_bfloat16, u));
}

// ---------------------------------------------------------------------------
// K_PREP: fused recurrence + pack + transpose (block-range dispatch).
// ---------------------------------------------------------------------------
#define NB_RECUR 8
#define NB_PACK  2048
#define NB_TR    512

__global__ __launch_bounds__(256) void k_prep(const float* __restrict__ src,
                                              const float* __restrict__ tgt,
                                              const float* __restrict__ enc,
                                              __hip_bfloat16* __restrict__ qb,
                                              __hip_bfloat16* __restrict__ kb,
                                              __hip_bfloat16* __restrict__ cb,
                                              __hip_bfloat16* __restrict__ tT) {
  __shared__ float tile[64][65];                   // used by transpose branch only
  const int bid = blockIdx.x;
  const int tid = threadIdx.x;

  if (bid < NB_RECUR) {
    // ---- serial recurrence: c_t = tanh(cc*pe); cc' = k_t*c_t; cc_0 = k_0 ----
    int g = bid * 256 + tid;                       // 0..2047
    int d = g & 63;
    int bh = g >> 6;
    int h = bh & 7;
    int b = bh >> 3;
    float pe = enc[h * D_DIM + d];
    float pe2 = 2.0f * pe;                         // tanh(x)=sgn(x)(1-e)/(1+e), e=exp(-2|x|)
    const float* tp = tgt + (size_t)b * S_LEN * E_DIM + h * D_DIM + d;
    __hip_bfloat16* cp = cb + (size_t)bh * S_LEN * D_DIM + d;

    constexpr int CH = 32;                         // prefetch chunk (registers)
    float bufA[CH], bufB[CH];
#pragma unroll
    for (int i = 0; i < CH; ++i) bufA[i] = tp[(size_t)i * E_DIM];
    float cc = bufA[0];                            // carry_0 = k_0

#pragma unroll 1
    for (int ch = 0; ch < S_LEN / CH; ch += 2) {
      if (ch + 1 < S_LEN / CH) {
#pragma unroll
        for (int i = 0; i < CH; ++i)
          bufB[i] = tp[(size_t)((ch + 1) * CH + i) * E_DIM];
      }
#pragma unroll
      for (int i = 0; i < CH; ++i) {
        float m = cc * pe2;
        float e = __expf(-fabsf(m));               // abs/neg fold to input mods
        float th = __builtin_copysignf((1.0f - e) * __builtin_amdgcn_rcpf(1.0f + e), m);
        cp[(size_t)(ch * CH + i) * D_DIM] = __float2bfloat16(th);
        cc = bufA[i] * th;
      }
      if (ch + 2 < S_LEN / CH) {
#pragma unroll
        for (int i = 0; i < CH; ++i)
          bufA[i] = tp[(size_t)((ch + 2) * CH + i) * E_DIM];
      }
#pragma unroll
      for (int i = 0; i < CH; ++i) {
        float m = cc * pe2;
        float e = __expf(-fabsf(m));
        float th = __builtin_copysignf((1.0f - e) * __builtin_amdgcn_rcpf(1.0f + e), m);
        cp[(size_t)((ch + 1) * CH + i) * D_DIM] = __float2bfloat16(th);
        cc = bufB[i] * th;
      }
    }
  } else if (bid < NB_RECUR + NB_PACK) {
    // ---- pack src/tgt (b,s,e) fp32 -> (bh,s,d) bf16, 4 elts/thread ----
    size_t i4 = ((size_t)(bid - NB_RECUR) * 256 + tid) * 4;   // < 2M
    float4 s4 = *reinterpret_cast<const float4*>(src + i4);
    float4 t4 = *reinterpret_cast<const float4*>(tgt + i4);
    int e = (int)(i4 & 511);                       // e%4==0, within one head (D=64)
    size_t bs = i4 >> 9;
    int s = (int)(bs & 1023);
    int b = (int)(bs >> 10);
    int h = e >> 6, d = e & 63;
    size_t o = (((size_t)(b * H_NUM + h) * S_LEN) + s) * D_DIM + d;
    us4 qv = {f2bf(s4.x), f2bf(s4.y), f2bf(s4.z), f2bf(s4.w)};
    us4 kv = {f2bf(t4.x), f2bf(t4.y), f2bf(t4.z), f2bf(t4.w)};
    *reinterpret_cast<us4*>(qb + o) = qv;
    *reinterpret_cast<us4*>(kb + o) = kv;
  } else {
    // ---- transpose tgt (b,s,e) -> tT (b,e,s) bf16, 64x64 tiles ----
    int lb = bid - (NB_RECUR + NB_PACK);           // 0..511
    int sx = lb & 15, ey = (lb >> 4) & 7, b = lb >> 7;
    int e0 = ey * 64, s0 = sx * 64;
    int tx = tid & 63, ty = tid >> 6;              // ty 0..3
    const float* p = tgt + ((size_t)b * S_LEN + s0) * E_DIM + e0;
#pragma unroll
    for (int r = ty; r < 64; r += 4) tile[r][tx] = p[(size_t)r * E_DIM + tx];
    __syncthreads();
    __hip_bfloat16* q = tT + ((size_t)b * E_DIM + e0) * S_LEN + s0;
#pragma unroll
    for (int r = ty; r < 64; r += 4) q[(size_t)r * S_LEN + tx] = __float2bfloat16(tile[tx][r]);
  }
}

// ---------------------------------------------------------------------------
// K3: attention weights.
// v8 = v7 body wrapped in a PERSISTENT work loop:
//   Elimination table (v2..v7): vmcnt depth, LDS size, staging granularity,
//   per-phase duty, reg-frag pipelining -> ALL null at ~51 us; occupancy
//   pinned ~18% (~1.5 blocks/CU) while 3-6 fit statically. Arithmetic:
//   2048 blocks x ~6 us at ~1 block/CU = 8 rounds = ~50 us -> the limiter
//   is block TURNOVER, not anything inside the block.
//   Fix: 512 blocks (exactly 2/CU, resident for the whole kernel), each
//   sequentially runs 4 s-tiles of ONE bh (items share cb/kb -> L2-warm).
//   Body per item is v7 verbatim; the two __syncthreads per item already
//   order red0/red1 reuse across items (writes are sync-separated from
//   prior reads) and their full drains cut cross-item vm/ds hazards.
//   LDS 64.5 KB x 2 = 129 <= 160. VGPR ~88.
// Null here => hard per-CU cap, k_weights closed; pivot to kg 8-phase.
// ---------------------------------------------------------------------------
__global__ __launch_bounds__(256) void k_weights(const __hip_bfloat16* __restrict__ qb,
                                                 const __hip_bfloat16* __restrict__ kb,
                                                 const __hip_bfloat16* __restrict__ cb,
                                                 __hip_bfloat16* __restrict__ wt,
                                                 const float* __restrict__ pal,
                                                 const float* __restrict__ pbe,
                                                 const float* __restrict__ pga) {
  // [wave][buf][c: ushort 0..1023 | k: ushort 1024..2047]  => 64 KB
  __shared__ unsigned short stage[4][4][2048];
  __shared__ float red0[4][16];                    // per-wave l_g partials
  __shared__ float red1[4][16];                    // per-wave l_w partials

  const int tid = threadIdx.x;
  const int wave = tid >> 6, lane = tid & 63;
  const int quad = lane >> 4, col = lane & 15;

  // Persistent decode: 512 blocks; xcd = g&7 (round-robin), j = g>>3.
  const int g = blockIdx.x;                        // 0..511
  const int xcd = g & 7;
  const int j = g >> 3;                            // 0..63
  const int bh = xcd * 4 + (j >> 4);               // 4 bh per XCD
  const int sbase = (j & 15) * 64;                 // 4 items x 16 s-rows

  const float alpha = pal[0], beta = pbe[0];
  const float inv_gamma = 1.0f / pga[0];
  const float sa = alpha * 0.01f * inv_gamma;      // semantic scale folded
  const float sb = beta * inv_gamma;

  const int t_base = wave * 256;
  const char* cbase = (const char*)(cb + ((size_t)bh * S_LEN + t_base) * D_DIM);
  const char* kbase = (const char*)(kb + ((size_t)bh * S_LEN + t_base) * D_DIM);
  const int so0 = ((lane >> 3) << 7) | (((lane & 7) ^ ((lane >> 3) & 7)) << 4);

  auto stage_it = [&](int it) {
    unsigned short* db = &stage[wave][it & 3][0];
    const char* cs = cbase + it * 2048;
    const char* ks = kbase + it * 2048;
    __builtin_amdgcn_global_load_lds((gas_uint*)(cs + so0),        (las_uint*)(db),        16, 0, 0);
    __builtin_amdgcn_global_load_lds((gas_uint*)(cs + so0 + 1024), (las_uint*)(db + 512),  16, 0, 0);
    __builtin_amdgcn_global_load_lds((gas_uint*)(ks + so0),        (las_uint*)(db + 1024), 16, 0, 0);
    __builtin_amdgcn_global_load_lds((gas_uint*)(ks + so0 + 1024), (las_uint*)(db + 1536), 16, 0, 0);
  };

  const int xswz = (col & 7) << 4;                 // read-side swizzle (row = col)
  const int rb = col * 128;

#pragma unroll 1
  for (int item = 0; item < 4; ++item) {
    const int s0 = sbase + item * 16;

    // A fragments (Q rows s0..s0+15), loaded per item.
    const __hip_bfloat16* qrow = qb + ((size_t)bh * S_LEN + s0 + col) * D_DIM;
    s16x8 a0 = *reinterpret_cast<const s16x8*>(qrow + quad * 8);
    s16x8 a1 = *reinterpret_cast<const s16x8*>(qrow + 32 + quad * 8);

    uint32_t stg[16][2];                           // g~ packed bf16 pairs (32 regs)
    float    stk[16][4];                           // qk logits fp32 (64 regs)

    s16x8 cF0[2], cF1[2], kF0[2], kF1[2];          // even/odd fragment slots

    // ---- pass 1: depth-2 tile pipeline + 1-iteration reg frags ----
    stage_it(0);
    stage_it(1);
    stage_it(2);                                   // 12 loads in flight
    asm volatile("s_waitcnt vmcnt(8)" ::: "memory"); // tile 0 landed
    {
      const char* cw = (const char*)&stage[wave][0][0];
      const char* kw = cw + 2048;
      cF0[0] = *reinterpret_cast<const s16x8*>(cw + rb + ((quad * 16) ^ xswz));
      cF1[0] = *reinterpret_cast<const s16x8*>(cw + rb + ((64 + quad * 16) ^ xswz));
      kF0[0] = *reinterpret_cast<const s16x8*>(kw + rb + ((quad * 16) ^ xswz));
      kF1[0] = *reinterpret_cast<const s16x8*>(kw + rb + ((64 + quad * 16) ^ xswz));
    }

    float lg[4] = {0.f, 0.f, 0.f, 0.f};
#pragma unroll
    for (int it = 0; it < 16; ++it) {
      if (it + 3 < 16) stage_it(it + 3);           // buf (it-1)&3: reads drained
      if (it < 13)       asm volatile("s_waitcnt vmcnt(8)" ::: "memory");
      else if (it == 13) asm volatile("s_waitcnt vmcnt(4)" ::: "memory");
      else if (it == 14) asm volatile("s_waitcnt vmcnt(0)" ::: "memory");
      if (it < 15) {                               // prefetch frags(it+1)
        const char* cw = (const char*)&stage[wave][(it + 1) & 3][0];
        const char* kw = cw + 2048;
        const int sl = (it + 1) & 1;               // compile-time under unroll
        cF0[sl] = *reinterpret_cast<const s16x8*>(cw + rb + ((quad * 16) ^ xswz));
        cF1[sl] = *reinterpret_cast<const s16x8*>(cw + rb + ((64 + quad * 16) ^ xswz));
        kF0[sl] = *reinterpret_cast<const s16x8*>(kw + rb + ((quad * 16) ^ xswz));
        kF1[sl] = *reinterpret_cast<const s16x8*>(kw + rb + ((64 + quad * 16) ^ xswz));
      }
      const int cur = it & 1;
      f32x4 dg = {0.f, 0.f, 0.f, 0.f};
      f32x4 dk = {0.f, 0.f, 0.f, 0.f};
      __builtin_amdgcn_s_setprio(1);
      dg = __builtin_amdgcn_mfma_f32_16x16x32_bf16(a0, cF0[cur], dg, 0, 0, 0);
      dg = __builtin_amdgcn_mfma_f32_16x16x32_bf16(a1, cF1[cur], dg, 0, 0, 0);
      dk = __builtin_amdgcn_mfma_f32_16x16x32_bf16(a0, kF0[cur], dk, 0, 0, 0);
      dk = __builtin_amdgcn_mfma_f32_16x16x32_bf16(a1, kF1[cur], dk, 0, 0, 0);
      __builtin_amdgcn_s_setprio(0);
      uint32_t p0 = 0, p1 = 0;
#pragma unroll
      for (int i = 0; i < 4; ++i) {
        float gv = __expf(dg[i] * 0.125f);         // /sqrt(D)
        unsigned short u = f2bf(gv);
        lg[i] += bf2f(u);                          // sum the ROUNDED value (consistent)
        if (i < 2) p0 |= (uint32_t)u << (16 * i);
        else       p1 |= (uint32_t)u << (16 * (i - 2));
        stk[it][i] = dk[i];
      }
      stg[it][0] = p0;
      stg[it][1] = p1;
    }
#pragma unroll
    for (int m = 1; m < 16; m <<= 1) {
#pragma unroll
      for (int i = 0; i < 4; ++i) lg[i] += __shfl_xor(lg[i], m);
    }
    if (col == 0) {
#pragma unroll
      for (int i = 0; i < 4; ++i) red0[wave][quad * 4 + i] = lg[i];
    }
    __syncthreads();
    float ilg[4];
#pragma unroll
    for (int i = 0; i < 4; ++i) {
      int rr = quad * 4 + i;
      ilg[i] = 1.0f / (red0[0][rr] + red0[1][rr] + red0[2][rr] + red0[3][rr]);
    }

    // ---- pass 2 (register-only): combine + l_w ----
    float lw[4] = {0.f, 0.f, 0.f, 0.f};
#pragma unroll
    for (int it = 0; it < 16; ++it) {
#pragma unroll
      for (int i = 0; i < 4; ++i) {
        unsigned short u = (unsigned short)((i < 2 ? stg[it][0] >> (16 * i)
                                                   : stg[it][1] >> (16 * (i - 2))) & 0xffffu);
        float gv = bf2f(u) * ilg[i];
        float z = sa * stk[it][i] + sb * gv;
        float wv = __expf(z);
        stk[it][i] = wv;
        lw[i] += wv;
      }
    }
#pragma unroll
    for (int m = 1; m < 16; m <<= 1) {
#pragma unroll
      for (int i = 0; i < 4; ++i) lw[i] += __shfl_xor(lw[i], m);
    }
    if (col == 0) {
#pragma unroll
      for (int i = 0; i < 4; ++i) red1[wave][quad * 4 + i] = lw[i];
    }
    __syncthreads();
    float ilw[4];
#pragma unroll
    for (int i = 0; i < 4; ++i) {
      int rr = quad * 4 + i;
      ilw[i] = 1.0f / (red1[0][rr] + red1[1][rr] + red1[2][rr] + red1[3][rr]);
    }

    // ---- pass 3: normalize + write wt (t, s) layout ----
    __hip_bfloat16* wrow = wt + ((size_t)bh * S_LEN + t_base + col) * S_LEN + s0 + quad * 4;
#pragma unroll
    for (int it = 0; it < 16; ++it) {
      us4 o;
#pragma unroll
      for (int i = 0; i < 4; ++i) o[i] = f2bf(stk[it][i] * ilw[i]);
      *reinterpret_cast<us4*>(wrow + (size_t)it * 16 * S_LEN) = o;
    }
  }
}

// ---------------------------------------------------------------------------
// K4: out[bh, t, e] = sum_s wt[bh][t][s] * tT[b][e][s]   (BT-GEMM)
// v2: double-buffered LDS (2x32 KB) + counted s_waitcnt vmcnt(8) + T2 XOR
//     swizzle (rule 21) + T5 setprio. Unchanged (proven ~48.5 us).
// ---------------------------------------------------------------------------
__global__ __launch_bounds__(256) void k_outgemm(const __hip_bfloat16* __restrict__ wt,
                                                 const __hip_bfloat16* __restrict__ tT,
                                                 float* __restrict__ out) {
  __shared__ __hip_bfloat16 As[2][128 * 64];       // [buf][m][k] 2x16 KB
  __shared__ __hip_bfloat16 Bs[2][128 * 64];       // [buf][n][k] 2x16 KB
  const int tid = threadIdx.x;
  const int wave = tid >> 6, lane = tid & 63;
  const int quad = lane >> 4, col = lane & 15;

  const int g = blockIdx.x;                        // 0..1023
  const int xcd = g & 7;
  const int local = g >> 3;                        // 0..127
  const int strip = xcd * 32 + (local >> 2);       // 0..255 = (bh, mtile)
  const int ntile = local & 3;
  const int bh = strip >> 3;
  const int mt = strip & 7;
  const int b = bh >> 3;
  const int m0 = mt * 128;                         // t
  const int n0 = ntile * 128;                      // e

  const __hip_bfloat16* Ag = wt + (size_t)bh * S_LEN * S_LEN;   // row stride S
  const __hip_bfloat16* Bg = tT + (size_t)b * E_DIM * S_LEN;    // row stride S
  const int mw = (wave >> 1) * 64, nw = (wave & 1) * 64;
  const int lrow = lane >> 3;                      // 0..7 (= dest row & 7)
  const int lcolswz = ((lane & 7) ^ lrow) * 8;     // inverse-swizzled src col

  f32x4 acc[4][4];
#pragma unroll
  for (int i = 0; i < 4; ++i)
#pragma unroll
    for (int j = 0; j < 4; ++j) acc[i][j] = (f32x4){0.f, 0.f, 0.f, 0.f};

  // stage one K-tile (8 global_load_lds per thread-wave: 4 A + 4 B)
  auto stage = [&](int kt, int buf) {
    const int k0 = kt * 64;
#pragma unroll
    for (int j = 0; j < 4; ++j) {
      const int rbase = j * 32 + wave * 8;
      const __hip_bfloat16* gpA = Ag + (size_t)(m0 + rbase + lrow) * S_LEN + k0 + lcolswz;
      __builtin_amdgcn_global_load_lds((gas_uint*)gpA,
                                       (las_uint*)(&As[buf][rbase * 64]), 16, 0, 0);
      const __hip_bfloat16* gpB = Bg + (size_t)(n0 + rbase + lrow) * S_LEN + k0 + lcolswz;
      __builtin_amdgcn_global_load_lds((gas_uint*)gpB,
                                       (las_uint*)(&Bs[buf][rbase * 64]), 16, 0, 0);
    }
  };

  const int swz = (col & 7) << 4;                  // read-side swizzle (row&7 = col&7)
  auto compute = [&](int buf) {
    const char* Ab = (const char*)&As[buf][0];
    const char* Bb = (const char*)&Bs[buf][0];
    __builtin_amdgcn_s_setprio(1);
#pragma unroll
    for (int ks = 0; ks < 2; ++ks) {
      s16x8 af[4], bfr[4];
#pragma unroll
      for (int i = 0; i < 4; ++i)
        af[i] = *reinterpret_cast<const s16x8*>(
            Ab + (size_t)(mw + i * 16 + col) * 128 + ((ks * 64 + quad * 16) ^ swz));
#pragma unroll
      for (int i = 0; i < 4; ++i)
        bfr[i] = *reinterpret_cast<const s16x8*>(
            Bb + (size_t)(nw + i * 16 + col) * 128 + ((ks * 64 + quad * 16) ^ swz));
#pragma unroll
      for (int mi = 0; mi < 4; ++mi)
#pragma unroll
        for (int ni = 0; ni < 4; ++ni)
          acc[mi][ni] = __builtin_amdgcn_mfma_f32_16x16x32_bf16(af[mi], bfr[ni], acc[mi][ni], 0, 0, 0);
    }
    __builtin_amdgcn_s_setprio(0);
  };

  stage(0, 0);
#pragma unroll 1
  for (int kt = 0; kt < 15; ++kt) {
    stage(kt + 1, (kt + 1) & 1);                   // prefetch next tile (8 ops in flight)
    asm volatile("s_waitcnt vmcnt(8)" ::: "memory"); // wait ONLY for buf[kt]'s 8 ops
    __builtin_amdgcn_s_barrier();                  // all waves' buf[kt] data landed
    compute(kt & 1);
    asm volatile("" ::: "memory");
    __builtin_amdgcn_s_barrier();                  // reads done before buf[kt] overwrite
  }
  asm volatile("s_waitcnt vmcnt(0)" ::: "memory"); // last tile: drain
  __builtin_amdgcn_s_barrier();
  compute(1);                                      // kt = 15 -> buf 1

  // epilogue: C row = quad*4+reg (m), col = lane&15 (n)
#pragma unroll
  for (int mi = 0; mi < 4; ++mi)
#pragma unroll
    for (int ni = 0; ni < 4; ++ni)
#pragma unroll
      for (int i = 0; i < 4; ++i) {
        int m = m0 + mw + mi * 16 + quad * 4 + i;
        int n = n0 + nw + ni * 16 + col;
        out[((size_t)bh * S_LEN + m) * E_DIM + n] = acc[mi][ni][i];
      }
}

// ---------------------------------------------------------------------------
// Workspace layout (bytes):
//   qb  [0,   4M)   (BH,S,D) bf16
//   kb  [4M,  8M)
//   cb  [8M, 12M)
//   tT  [12M,16M)   (B,E,S) bf16
//   wt  [16M,80M)   (BH,S_t,S_s) bf16
// ---------------------------------------------------------------------------
extern "C" void kernel_launch(void* const* d_in, const int* in_sizes, int n_in,
                              void* d_out, int out_size, void* d_ws, size_t ws_size,
                              hipStream_t stream) {
  (void)in_sizes; (void)n_in; (void)out_size; (void)ws_size;
  const float* src = (const float*)d_in[0];
  const float* tgt = (const float*)d_in[1];
  const float* enc = (const float*)d_in[2];
  const float* pal = (const float*)d_in[3];
  const float* pbe = (const float*)d_in[4];
  const float* pga = (const float*)d_in[5];
  float* out = (float*)d_out;

  char* ws = (char*)d_ws;
  __hip_bfloat16* qb = (__hip_bfloat16*)(ws);
  __hip_bfloat16* kb = (__hip_bfloat16*)(ws + ((size_t)4 << 20));
  __hip_bfloat16* cb = (__hip_bfloat16*)(ws + ((size_t)8 << 20));
  __hip_bfloat16* tT = (__hip_bfloat16*)(ws + ((size_t)12 << 20));
  __hip_bfloat16* wt = (__hip_bfloat16*)(ws + ((size_t)16 << 20));

  // Fused prep: recurrence (blocks 0..7) + pack + transpose
  k_prep<<<NB_RECUR + NB_PACK + NB_TR, 256, 0, stream>>>(src, tgt, enc, qb, kb, cb, tT);
  // K3: weights (v8: 512 persistent blocks x 4 work items, 2 blocks/CU)
  k_weights<<<dim3(512), 256, 0, stream>>>(qb, kb, cb, wt, pal, pbe, pga);
  // K4: output GEMM (1D swizzled grid)
  k_outgemm<<<dim3((E_DIM / 128) * (S_LEN / 128) * BH_NUM), 256, 0, stream>>>(wt, tT, out);
}

// Round 11
// 208.359 us; speedup vs baseline: 1.0948x; 1.0948x over previous
//
#include <hip/hip_runtime.h>
#include <hip/hip_bf16.h>
#include <stdint.h>

// Problem constants: B=4, S=1024, E=512, H=8, D=64
#define S_LEN 1024
#define E_DIM 512
#define H_NUM 8
#define D_DIM 64
#define B_NUM 4
#define BH_NUM 32

using s16x8 = __attribute__((ext_vector_type(8))) short;           // 8 bf16 (4 VGPRs)
using f32x4 = __attribute__((ext_vector_type(4))) float;           // MFMA accumulator
using us4   = __attribute__((ext_vector_type(4))) unsigned short;  // 4 bf16 (8 B)

typedef const __attribute__((address_space(1))) uint32_t gas_uint;
typedef __attribute__((address_space(3))) uint32_t las_uint;

static __device__ __forceinline__ unsigned short f2bf(float f) {
  __hip_bfloat16 h = __float2bfloat16(f);
  return __builtin_bit_cast(unsigned short, h);
}
static __device__ __forceinline__ float bf2f(unsigned short u) {
  return __bfloat162float(__builtin_bit_cast(__hip_bfloat16, u));
}

// ---------------------------------------------------------------------------
// K_PREP: fused recurrence + pack + transpose (block-range dispatch).
// v2 (resubmit after container-level infra failure, same precedent as R5->R6;
//     audited: tanh rewrite saturates correctly at +/-1, no NaN/inf path,
//     addressing untouched):
//   recurrence chain shortened 8 -> 6 dependent ops:
//   tanh(x) = 1 - 2/(exp2(x*2log2e)+1); the log2e mul folds into the
//   precomputed peC, (1-e)/(1+e)+copysign collapse to fma(-2,rcp,1).
// ---------------------------------------------------------------------------
#define NB_RECUR 8
#define NB_PACK  2048
#define NB_TR    512

__global__ __launch_bounds__(256) void k_prep(const float* __restrict__ src,
                                              const float* __restrict__ tgt,
                                              const float* __restrict__ enc,
                                              __hip_bfloat16* __restrict__ qb,
                                              __hip_bfloat16* __restrict__ kb,
                                              __hip_bfloat16* __restrict__ cb,
                                              __hip_bfloat16* __restrict__ tT) {
  __shared__ float tile[64][65];                   // used by transpose branch only
  const int bid = blockIdx.x;
  const int tid = threadIdx.x;

  if (bid < NB_RECUR) {
    // ---- serial recurrence: c_t = tanh(cc*pe); cc' = k_t*c_t; cc_0 = k_0 ----
    int g = bid * 256 + tid;                       // 0..2047
    int d = g & 63;
    int bh = g >> 6;
    int h = bh & 7;
    int b = bh >> 3;
    float pe = enc[h * D_DIM + d];
    float peC = pe * 2.8853900817779268f;          // 2*log2(e)*pe
    const float* tp = tgt + (size_t)b * S_LEN * E_DIM + h * D_DIM + d;
    __hip_bfloat16* cp = cb + (size_t)bh * S_LEN * D_DIM + d;

    constexpr int CH = 32;                         // prefetch chunk (registers)
    float bufA[CH], bufB[CH];
#pragma unroll
    for (int i = 0; i < CH; ++i) bufA[i] = tp[(size_t)i * E_DIM];
    float cc = bufA[0];                            // carry_0 = k_0

#pragma unroll 1
    for (int ch = 0; ch < S_LEN / CH; ch += 2) {
      if (ch + 1 < S_LEN / CH) {
#pragma unroll
        for (int i = 0; i < CH; ++i)
          bufB[i] = tp[(size_t)((ch + 1) * CH + i) * E_DIM];
      }
#pragma unroll
      for (int i = 0; i < CH; ++i) {
        float v = exp2f(cc * peC);                 // 2^(2x*log2e) = e^(2x)
        float r = __builtin_amdgcn_rcpf(v + 1.0f);
        float th = fmaf(-2.0f, r, 1.0f);           // tanh(x)
        cp[(size_t)(ch * CH + i) * D_DIM] = __float2bfloat16(th);
        cc = bufA[i] * th;
      }
      if (ch + 2 < S_LEN / CH) {
#pragma unroll
        for (int i = 0; i < CH; ++i)
          bufA[i] = tp[(size_t)((ch + 2) * CH + i) * E_DIM];
      }
#pragma unroll
      for (int i = 0; i < CH; ++i) {
        float v = exp2f(cc * peC);
        float r = __builtin_amdgcn_rcpf(v + 1.0f);
        float th = fmaf(-2.0f, r, 1.0f);
        cp[(size_t)((ch + 1) * CH + i) * D_DIM] = __float2bfloat16(th);
        cc = bufB[i] * th;
      }
    }
  } else if (bid < NB_RECUR + NB_PACK) {
    // ---- pack src/tgt (b,s,e) fp32 -> (bh,s,d) bf16, 4 elts/thread ----
    size_t i4 = ((size_t)(bid - NB_RECUR) * 256 + tid) * 4;   // < 2M
    float4 s4 = *reinterpret_cast<const float4*>(src + i4);
    float4 t4 = *reinterpret_cast<const float4*>(tgt + i4);
    int e = (int)(i4 & 511);                       // e%4==0, within one head (D=64)
    size_t bs = i4 >> 9;
    int s = (int)(bs & 1023);
    int b = (int)(bs >> 10);
    int h = e >> 6, d = e & 63;
    size_t o = (((size_t)(b * H_NUM + h) * S_LEN) + s) * D_DIM + d;
    us4 qv = {f2bf(s4.x), f2bf(s4.y), f2bf(s4.z), f2bf(s4.w)};
    us4 kv = {f2bf(t4.x), f2bf(t4.y), f2bf(t4.z), f2bf(t4.w)};
    *reinterpret_cast<us4*>(qb + o) = qv;
    *reinterpret_cast<us4*>(kb + o) = kv;
  } else {
    // ---- transpose tgt (b,s,e) -> tT (b,e,s) bf16, 64x64 tiles ----
    int lb = bid - (NB_RECUR + NB_PACK);           // 0..511
    int sx = lb & 15, ey = (lb >> 4) & 7, b = lb >> 7;
    int e0 = ey * 64, s0 = sx * 64;
    int tx = tid & 63, ty = tid >> 6;              // ty 0..3
    const float* p = tgt + ((size_t)b * S_LEN + s0) * E_DIM + e0;
#pragma unroll
    for (int r = ty; r < 64; r += 4) tile[r][tx] = p[(size_t)r * E_DIM + tx];
    __syncthreads();
    __hip_bfloat16* q = tT + ((size_t)b * E_DIM + e0) * S_LEN + s0;
#pragma unroll
    for (int r = ty; r < 64; r += 4) q[(size_t)r * S_LEN + tx] = __float2bfloat16(tile[tx][r]);
  }
}

// ---------------------------------------------------------------------------
// K3: attention weights.
// v7 (reverted to after v8-persistent regression: VGPR 164, FETCH 3x, -25us):
//   depth-2 tile pipeline + 1-iteration register fragment prefetch.
//   kw is CLOSED at ~50.3 us: vmcnt depth, LDS size, granularity, duty,
//   reg-frag pipelining all null; persistence regresses via regalloc.
// ---------------------------------------------------------------------------
__global__ __launch_bounds__(256) void k_weights(const __hip_bfloat16* __restrict__ qb,
                                                 const __hip_bfloat16* __restrict__ kb,
                                                 const __hip_bfloat16* __restrict__ cb,
                                                 __hip_bfloat16* __restrict__ wt,
                                                 const float* __restrict__ pal,
                                                 const float* __restrict__ pbe,
                                                 const float* __restrict__ pga) {
  // [wave][buf][c: ushort 0..1023 | k: ushort 1024..2047]  => 64 KB
  __shared__ unsigned short stage[4][4][2048];
  __shared__ float red0[4][16];                    // per-wave l_g partials
  __shared__ float red1[4][16];                    // per-wave l_w partials

  const int tid = threadIdx.x;
  const int wave = tid >> 6, lane = tid & 63;
  const int quad = lane >> 4, col = lane & 15;

  // XCD-aware decode: xcd = g&7 (round-robin), r enumerates (bh-sub, s-tile)
  const int g = blockIdx.x;
  const int xcd = g & 7;
  const int r = g >> 3;                            // 0..255
  const int bh = xcd * 4 + (r >> 6);               // 4 bh per XCD
  const int s0 = (r & 63) * 16;

  const float alpha = pal[0], beta = pbe[0];
  const float inv_gamma = 1.0f / pga[0];
  const float sa = alpha * 0.01f * inv_gamma;      // semantic scale folded
  const float sb = beta * inv_gamma;

  // A fragments (Q rows s0..s0+15), loaded once, shared by both GEMMs.
  const __hip_bfloat16* qrow = qb + ((size_t)bh * S_LEN + s0 + col) * D_DIM;
  s16x8 a0 = *reinterpret_cast<const s16x8*>(qrow + quad * 8);
  s16x8 a1 = *reinterpret_cast<const s16x8*>(qrow + 32 + quad * 8);

  const int t_base = wave * 256;
  uint32_t stg[16][2];                             // g~ packed bf16 pairs (32 regs)
  float    stk[16][4];                             // qk logits fp32 (64 regs)

  // ---- pass 1: pipelined sweep, depth-2 tiles + 1-iteration reg frags ----
  const char* cbase = (const char*)(cb + ((size_t)bh * S_LEN + t_base) * D_DIM);
  const char* kbase = (const char*)(kb + ((size_t)bh * S_LEN + t_base) * D_DIM);
  const int so0 = ((lane >> 3) << 7) | (((lane & 7) ^ ((lane >> 3) & 7)) << 4);

  auto stage_it = [&](int it) {
    unsigned short* db = &stage[wave][it & 3][0];
    const char* cs = cbase + it * 2048;
    const char* ks = kbase + it * 2048;
    __builtin_amdgcn_global_load_lds((gas_uint*)(cs + so0),        (las_uint*)(db),        16, 0, 0);
    __builtin_amdgcn_global_load_lds((gas_uint*)(cs + so0 + 1024), (las_uint*)(db + 512),  16, 0, 0);
    __builtin_amdgcn_global_load_lds((gas_uint*)(ks + so0),        (las_uint*)(db + 1024), 16, 0, 0);
    __builtin_amdgcn_global_load_lds((gas_uint*)(ks + so0 + 1024), (las_uint*)(db + 1536), 16, 0, 0);
  };

  const int xswz = (col & 7) << 4;                 // read-side swizzle (row = col)
  const int rb = col * 128;

  s16x8 cF0[2], cF1[2], kF0[2], kF1[2];            // even/odd fragment slots

  stage_it(0);
  stage_it(1);
  stage_it(2);                                     // 12 loads in flight
  asm volatile("s_waitcnt vmcnt(8)" ::: "memory"); // tile 0 landed
  {
    const char* cw = (const char*)&stage[wave][0][0];
    const char* kw = cw + 2048;
    cF0[0] = *reinterpret_cast<const s16x8*>(cw + rb + ((quad * 16) ^ xswz));
    cF1[0] = *reinterpret_cast<const s16x8*>(cw + rb + ((64 + quad * 16) ^ xswz));
    kF0[0] = *reinterpret_cast<const s16x8*>(kw + rb + ((quad * 16) ^ xswz));
    kF1[0] = *reinterpret_cast<const s16x8*>(kw + rb + ((64 + quad * 16) ^ xswz));
  }

  float lg[4] = {0.f, 0.f, 0.f, 0.f};
#pragma unroll
  for (int it = 0; it < 16; ++it) {
    // issue next-next-next tile (overwrites buf (it-1)&3: reads drained
    // before MFMA(it-1) last iteration)
    if (it + 3 < 16) stage_it(it + 3);
    // wait tile it+1 landed (tiles it+2, it+3 = 8 loads may stay in flight)
    if (it < 13)       asm volatile("s_waitcnt vmcnt(8)" ::: "memory");
    else if (it == 13) asm volatile("s_waitcnt vmcnt(4)" ::: "memory");
    else if (it == 14) asm volatile("s_waitcnt vmcnt(0)" ::: "memory");
    // prefetch frags(it+1) into the other slot (consumed NEXT iteration ->
    // ds_read latency crosses a full iteration of compute)
    if (it < 15) {
      const char* cw = (const char*)&stage[wave][(it + 1) & 3][0];
      const char* kw = cw + 2048;
      const int sl = (it + 1) & 1;                 // compile-time under unroll
      cF0[sl] = *reinterpret_cast<const s16x8*>(cw + rb + ((quad * 16) ^ xswz));
      cF1[sl] = *reinterpret_cast<const s16x8*>(cw + rb + ((64 + quad * 16) ^ xswz));
      kF0[sl] = *reinterpret_cast<const s16x8*>(kw + rb + ((quad * 16) ^ xswz));
      kF1[sl] = *reinterpret_cast<const s16x8*>(kw + rb + ((64 + quad * 16) ^ xswz));
    }
    // compute on frags(it): loaded one iteration ago, lgkm wait is free
    const int cur = it & 1;
    f32x4 dg = {0.f, 0.f, 0.f, 0.f};
    f32x4 dk = {0.f, 0.f, 0.f, 0.f};
    __builtin_amdgcn_s_setprio(1);
    dg = __builtin_amdgcn_mfma_f32_16x16x32_bf16(a0, cF0[cur], dg, 0, 0, 0);
    dg = __builtin_amdgcn_mfma_f32_16x16x32_bf16(a1, cF1[cur], dg, 0, 0, 0);
    dk = __builtin_amdgcn_mfma_f32_16x16x32_bf16(a0, kF0[cur], dk, 0, 0, 0);
    dk = __builtin_amdgcn_mfma_f32_16x16x32_bf16(a1, kF1[cur], dk, 0, 0, 0);
    __builtin_amdgcn_s_setprio(0);
    // VALU tail: grammar exp + pack, qk stash
    uint32_t p0 = 0, p1 = 0;
#pragma unroll
    for (int i = 0; i < 4; ++i) {
      float gv = __expf(dg[i] * 0.125f);           // /sqrt(D)
      unsigned short u = f2bf(gv);
      lg[i] += bf2f(u);                            // sum the ROUNDED value (consistent)
      if (i < 2) p0 |= (uint32_t)u << (16 * i);
      else       p1 |= (uint32_t)u << (16 * (i - 2));
      stk[it][i] = dk[i];
    }
    stg[it][0] = p0;
    stg[it][1] = p1;
  }
#pragma unroll
  for (int m = 1; m < 16; m <<= 1) {
#pragma unroll
    for (int i = 0; i < 4; ++i) lg[i] += __shfl_xor(lg[i], m);
  }
  if (col == 0) {
#pragma unroll
    for (int i = 0; i < 4; ++i) red0[wave][quad * 4 + i] = lg[i];
  }
  __syncthreads();
  float ilg[4];
#pragma unroll
  for (int i = 0; i < 4; ++i) {
    int rr = quad * 4 + i;
    ilg[i] = 1.0f / (red0[0][rr] + red0[1][rr] + red0[2][rr] + red0[3][rr]);
  }

  // ---- pass 2 (register-only): combine + l_w ----
  float lw[4] = {0.f, 0.f, 0.f, 0.f};
#pragma unroll
  for (int it = 0; it < 16; ++it) {
#pragma unroll
    for (int i = 0; i < 4; ++i) {
      unsigned short u = (unsigned short)((i < 2 ? stg[it][0] >> (16 * i)
                                                 : stg[it][1] >> (16 * (i - 2))) & 0xffffu);
      float gv = bf2f(u) * ilg[i];
      float z = sa * stk[it][i] + sb * gv;
      float wv = __expf(z);
      stk[it][i] = wv;
      lw[i] += wv;
    }
  }
#pragma unroll
  for (int m = 1; m < 16; m <<= 1) {
#pragma unroll
    for (int i = 0; i < 4; ++i) lw[i] += __shfl_xor(lw[i], m);
  }
  if (col == 0) {
#pragma unroll
    for (int i = 0; i < 4; ++i) red1[wave][quad * 4 + i] = lw[i];
  }
  __syncthreads();
  float ilw[4];
#pragma unroll
  for (int i = 0; i < 4; ++i) {
    int rr = quad * 4 + i;
    ilw[i] = 1.0f / (red1[0][rr] + red1[1][rr] + red1[2][rr] + red1[3][rr]);
  }

  // ---- pass 3: normalize + write wt (t, s) layout ----
  __hip_bfloat16* wrow = wt + ((size_t)bh * S_LEN + t_base + col) * S_LEN + s0 + quad * 4;
#pragma unroll
  for (int it = 0; it < 16; ++it) {
    us4 o;
#pragma unroll
    for (int i = 0; i < 4; ++i) o[i] = f2bf(stk[it][i] * ilw[i]);
    *reinterpret_cast<us4*>(wrow + (size_t)it * 16 * S_LEN) = o;
  }
}

// ---------------------------------------------------------------------------
// K4: out[bh, t, e] = sum_s wt[bh][t][s] * tT[b][e][s]   (BT-GEMM)
// v2: double-buffered LDS (2x32 KB) + counted s_waitcnt vmcnt(8) + T2 XOR
//     swizzle (rule 21) + T5 setprio. Unchanged (proven ~48.5 us).
// ---------------------------------------------------------------------------
__global__ __launch_bounds__(256) void k_outgemm(const __hip_bfloat16* __restrict__ wt,
                                                 const __hip_bfloat16* __restrict__ tT,
                                                 float* __restrict__ out) {
  __shared__ __hip_bfloat16 As[2][128 * 64];       // [buf][m][k] 2x16 KB
  __shared__ __hip_bfloat16 Bs[2][128 * 64];       // [buf][n][k] 2x16 KB
  const int tid = threadIdx.x;
  const int wave = tid >> 6, lane = tid & 63;
  const int quad = lane >> 4, col = lane & 15;

  const int g = blockIdx.x;                        // 0..1023
  const int xcd = g & 7;
  const int local = g >> 3;                        // 0..127
  const int strip = xcd * 32 + (local >> 2);       // 0..255 = (bh, mtile)
  const int ntile = local & 3;
  const int bh = strip >> 3;
  const int mt = strip & 7;
  const int b = bh >> 3;
  const int m0 = mt * 128;                         // t
  const int n0 = ntile * 128;                      // e

  const __hip_bfloat16* Ag = wt + (size_t)bh * S_LEN * S_LEN;   // row stride S
  const __hip_bfloat16* Bg = tT + (size_t)b * E_DIM * S_LEN;    // row stride S
  const int mw = (wave >> 1) * 64, nw = (wave & 1) * 64;
  const int lrow = lane >> 3;                      // 0..7 (= dest row & 7)
  const int lcolswz = ((lane & 7) ^ lrow) * 8;     // inverse-swizzled src col

  f32x4 acc[4][4];
#pragma unroll
  for (int i = 0; i < 4; ++i)
#pragma unroll
    for (int j = 0; j < 4; ++j) acc[i][j] = (f32x4){0.f, 0.f, 0.f, 0.f};

  // stage one K-tile (8 global_load_lds per thread-wave: 4 A + 4 B)
  auto stage = [&](int kt, int buf) {
    const int k0 = kt * 64;
#pragma unroll
    for (int j = 0; j < 4; ++j) {
      const int rbase = j * 32 + wave * 8;
      const __hip_bfloat16* gpA = Ag + (size_t)(m0 + rbase + lrow) * S_LEN + k0 + lcolswz;
      __builtin_amdgcn_global_load_lds((gas_uint*)gpA,
                                       (las_uint*)(&As[buf][rbase * 64]), 16, 0, 0);
      const __hip_bfloat16* gpB = Bg + (size_t)(n0 + rbase + lrow) * S_LEN + k0 + lcolswz;
      __builtin_amdgcn_global_load_lds((gas_uint*)gpB,
                                       (las_uint*)(&Bs[buf][rbase * 64]), 16, 0, 0);
    }
  };

  const int swz = (col & 7) << 4;                  // read-side swizzle (row&7 = col&7)
  auto compute = [&](int buf) {
    const char* Ab = (const char*)&As[buf][0];
    const char* Bb = (const char*)&Bs[buf][0];
    __builtin_amdgcn_s_setprio(1);
#pragma unroll
    for (int ks = 0; ks < 2; ++ks) {
      s16x8 af[4], bfr[4];
#pragma unroll
      for (int i = 0; i < 4; ++i)
        af[i] = *reinterpret_cast<const s16x8*>(
            Ab + (size_t)(mw + i * 16 + col) * 128 + ((ks * 64 + quad * 16) ^ swz));
#pragma unroll
      for (int i = 0; i < 4; ++i)
        bfr[i] = *reinterpret_cast<const s16x8*>(
            Bb + (size_t)(nw + i * 16 + col) * 128 + ((ks * 64 + quad * 16) ^ swz));
#pragma unroll
      for (int mi = 0; mi < 4; ++mi)
#pragma unroll
        for (int ni = 0; ni < 4; ++ni)
          acc[mi][ni] = __builtin_amdgcn_mfma_f32_16x16x32_bf16(af[mi], bfr[ni], acc[mi][ni], 0, 0, 0);
    }
    __builtin_amdgcn_s_setprio(0);
  };

  stage(0, 0);
#pragma unroll 1
  for (int kt = 0; kt < 15; ++kt) {
    stage(kt + 1, (kt + 1) & 1);                   // prefetch next tile (8 ops in flight)
    asm volatile("s_waitcnt vmcnt(8)" ::: "memory"); // wait ONLY for buf[kt]'s 8 ops
    __builtin_amdgcn_s_barrier();                  // all waves' buf[kt] data landed
    compute(kt & 1);
    asm volatile("" ::: "memory");
    __builtin_amdgcn_s_barrier();                  // reads done before buf[kt] overwrite
  }
  asm volatile("s_waitcnt vmcnt(0)" ::: "memory"); // last tile: drain
  __builtin_amdgcn_s_barrier();
  compute(1);                                      // kt = 15 -> buf 1

  // epilogue: C row = quad*4+reg (m), col = lane&15 (n)
#pragma unroll
  for (int mi = 0; mi < 4; ++mi)
#pragma unroll
    for (int ni = 0; ni < 4; ++ni)
#pragma unroll
      for (int i = 0; i < 4; ++i) {
        int m = m0 + mw + mi * 16 + quad * 4 + i;
        int n = n0 + nw + ni * 16 + col;
        out[((size_t)bh * S_LEN + m) * E_DIM + n] = acc[mi][ni][i];
      }
}

// ---------------------------------------------------------------------------
// Workspace layout (bytes):
//   qb  [0,   4M)   (BH,S,D) bf16
//   kb  [4M,  8M)
//   cb  [8M, 12M)
//   tT  [12M,16M)   (B,E,S) bf16
//   wt  [16M,80M)   (BH,S_t,S_s) bf16
// ---------------------------------------------------------------------------
extern "C" void kernel_launch(void* const* d_in, const int* in_sizes, int n_in,
                              void* d_out, int out_size, void* d_ws, size_t ws_size,
                              hipStream_t stream) {
  (void)in_sizes; (void)n_in; (void)out_size; (void)ws_size;
  const float* src = (const float*)d_in[0];
  const float* tgt = (const float*)d_in[1];
  const float* enc = (const float*)d_in[2];
  const float* pal = (const float*)d_in[3];
  const float* pbe = (const float*)d_in[4];
  const float* pga = (const float*)d_in[5];
  float* out = (float*)d_out;

  char* ws = (char*)d_ws;
  __hip_bfloat16* qb = (__hip_bfloat16*)(ws);
  __hip_bfloat16* kb = (__hip_bfloat16*)(ws + ((size_t)4 << 20));
  __hip_bfloat16* cb = (__hip_bfloat16*)(ws + ((size_t)8 << 20));
  __hip_bfloat16* tT = (__hip_bfloat16*)(ws + ((size_t)12 << 20));
  __hip_bfloat16* wt = (__hip_bfloat16*)(ws + ((size_t)16 << 20));

  // Fused prep: recurrence (blocks 0..7) + pack + transpose
  k_prep<<<NB_RECUR + NB_PACK + NB_TR, 256, 0, stream>>>(src, tgt, enc, qb, kb, cb, tT);
  // K3: weights (v7 reverted: depth-2 tiles + reg fragment pipeline)
  k_weights<<<dim3((S_LEN / 16) * BH_NUM), 256, 0, stream>>>(qb, kb, cb, wt, pal, pbe, pga);
  // K4: output GEMM (1D swizzled grid)
  k_outgemm<<<dim3((E_DIM / 128) * (S_LEN / 128) * BH_NUM), 256, 0, stream>>>(wt, tT, out);
}

// Round 12
// 202.233 us; speedup vs baseline: 1.1279x; 1.0303x over previous
//
#include <hip/hip_runtime.h>
#include <hip/hip_bf16.h>
#include <stdint.h>

// Problem constants: B=4, S=1024, E=512, H=8, D=64
#define S_LEN 1024
#define E_DIM 512
#define H_NUM 8
#define D_DIM 64
#define B_NUM 4
#define BH_NUM 32

using s16x8 = __attribute__((ext_vector_type(8))) short;           // 8 bf16 (4 VGPRs)
using f32x4 = __attribute__((ext_vector_type(4))) float;           // MFMA accumulator
using us4   = __attribute__((ext_vector_type(4))) unsigned short;  // 4 bf16 (8 B)

typedef const __attribute__((address_space(1))) uint32_t gas_uint;
typedef __attribute__((address_space(3))) uint32_t las_uint;

static __device__ __forceinline__ unsigned short f2bf(float f) {
  __hip_bfloat16 h = __float2bfloat16(f);
  return __builtin_bit_cast(unsigned short, h);
}
static __device__ __forceinline__ float bf2f(unsigned short u) {
  return __bfloat162float(__builtin_bit_cast(__hip_bfloat16, u));
}

// ---------------------------------------------------------------------------
// K_PREP: fused recurrence + pack + transpose (block-range dispatch).
// Reverted to the original (pre-R9) recurrence: the tanh chain-shortening
// (R11) produced no total gain -> prep is not chain-bound; keep the version
// behind every 204-us-class result.
// ---------------------------------------------------------------------------
#define NB_RECUR 8
#define NB_PACK  2048
#define NB_TR    512

__global__ __launch_bounds__(256) void k_prep(const float* __restrict__ src,
                                              const float* __restrict__ tgt,
                                              const float* __restrict__ enc,
                                              __hip_bfloat16* __restrict__ qb,
                                              __hip_bfloat16* __restrict__ kb,
                                              __hip_bfloat16* __restrict__ cb,
                                              __hip_bfloat16* __restrict__ tT) {
  __shared__ float tile[64][65];                   // used by transpose branch only
  const int bid = blockIdx.x;
  const int tid = threadIdx.x;

  if (bid < NB_RECUR) {
    // ---- serial recurrence: c_t = tanh(cc*pe); cc' = k_t*c_t; cc_0 = k_0 ----
    int g = bid * 256 + tid;                       // 0..2047
    int d = g & 63;
    int bh = g >> 6;
    int h = bh & 7;
    int b = bh >> 3;
    float pe = enc[h * D_DIM + d];
    float pe2 = 2.0f * pe;                         // tanh(x)=sgn(x)(1-e)/(1+e), e=exp(-2|x|)
    const float* tp = tgt + (size_t)b * S_LEN * E_DIM + h * D_DIM + d;
    __hip_bfloat16* cp = cb + (size_t)bh * S_LEN * D_DIM + d;

    constexpr int CH = 32;                         // prefetch chunk (registers)
    float bufA[CH], bufB[CH];
#pragma unroll
    for (int i = 0; i < CH; ++i) bufA[i] = tp[(size_t)i * E_DIM];
    float cc = bufA[0];                            // carry_0 = k_0

#pragma unroll 1
    for (int ch = 0; ch < S_LEN / CH; ch += 2) {
      if (ch + 1 < S_LEN / CH) {
#pragma unroll
        for (int i = 0; i < CH; ++i)
          bufB[i] = tp[(size_t)((ch + 1) * CH + i) * E_DIM];
      }
#pragma unroll
      for (int i = 0; i < CH; ++i) {
        float m = cc * pe2;
        float e = __expf(-fabsf(m));               // abs/neg fold to input mods
        float th = __builtin_copysignf((1.0f - e) * __builtin_amdgcn_rcpf(1.0f + e), m);
        cp[(size_t)(ch * CH + i) * D_DIM] = __float2bfloat16(th);
        cc = bufA[i] * th;
      }
      if (ch + 2 < S_LEN / CH) {
#pragma unroll
        for (int i = 0; i < CH; ++i)
          bufA[i] = tp[(size_t)((ch + 2) * CH + i) * E_DIM];
      }
#pragma unroll
      for (int i = 0; i < CH; ++i) {
        float m = cc * pe2;
        float e = __expf(-fabsf(m));
        float th = __builtin_copysignf((1.0f - e) * __builtin_amdgcn_rcpf(1.0f + e), m);
        cp[(size_t)((ch + 1) * CH + i) * D_DIM] = __float2bfloat16(th);
        cc = bufB[i] * th;
      }
    }
  } else if (bid < NB_RECUR + NB_PACK) {
    // ---- pack src/tgt (b,s,e) fp32 -> (bh,s,d) bf16, 4 elts/thread ----
    size_t i4 = ((size_t)(bid - NB_RECUR) * 256 + tid) * 4;   // < 2M
    float4 s4 = *reinterpret_cast<const float4*>(src + i4);
    float4 t4 = *reinterpret_cast<const float4*>(tgt + i4);
    int e = (int)(i4 & 511);                       // e%4==0, within one head (D=64)
    size_t bs = i4 >> 9;
    int s = (int)(bs & 1023);
    int b = (int)(bs >> 10);
    int h = e >> 6, d = e & 63;
    size_t o = (((size_t)(b * H_NUM + h) * S_LEN) + s) * D_DIM + d;
    us4 qv = {f2bf(s4.x), f2bf(s4.y), f2bf(s4.z), f2bf(s4.w)};
    us4 kv = {f2bf(t4.x), f2bf(t4.y), f2bf(t4.z), f2bf(t4.w)};
    *reinterpret_cast<us4*>(qb + o) = qv;
    *reinterpret_cast<us4*>(kb + o) = kv;
  } else {
    // ---- transpose tgt (b,s,e) -> tT (b,e,s) bf16, 64x64 tiles ----
    int lb = bid - (NB_RECUR + NB_PACK);           // 0..511
    int sx = lb & 15, ey = (lb >> 4) & 7, b = lb >> 7;
    int e0 = ey * 64, s0 = sx * 64;
    int tx = tid & 63, ty = tid >> 6;              // ty 0..3
    const float* p = tgt + ((size_t)b * S_LEN + s0) * E_DIM + e0;
#pragma unroll
    for (int r = ty; r < 64; r += 4) tile[r][tx] = p[(size_t)r * E_DIM + tx];
    __syncthreads();
    __hip_bfloat16* q = tT + ((size_t)b * E_DIM + e0) * S_LEN + s0;
#pragma unroll
    for (int r = ty; r < 64; r += 4) q[(size_t)r * S_LEN + tx] = __float2bfloat16(tile[tx][r]);
  }
}

// ---------------------------------------------------------------------------
// K3: attention weights (v7, proven ~50.3 us; kw closed).
// ---------------------------------------------------------------------------
__global__ __launch_bounds__(256) void k_weights(const __hip_bfloat16* __restrict__ qb,
                                                 const __hip_bfloat16* __restrict__ kb,
                                                 const __hip_bfloat16* __restrict__ cb,
                                                 __hip_bfloat16* __restrict__ wt,
                                                 const float* __restrict__ pal,
                                                 const float* __restrict__ pbe,
                                                 const float* __restrict__ pga) {
  // [wave][buf][c: ushort 0..1023 | k: ushort 1024..2047]  => 64 KB
  __shared__ unsigned short stage[4][4][2048];
  __shared__ float red0[4][16];                    // per-wave l_g partials
  __shared__ float red1[4][16];                    // per-wave l_w partials

  const int tid = threadIdx.x;
  const int wave = tid >> 6, lane = tid & 63;
  const int quad = lane >> 4, col = lane & 15;

  // XCD-aware decode: xcd = g&7 (round-robin), r enumerates (bh-sub, s-tile)
  const int g = blockIdx.x;
  const int xcd = g & 7;
  const int r = g >> 3;                            // 0..255
  const int bh = xcd * 4 + (r >> 6);               // 4 bh per XCD
  const int s0 = (r & 63) * 16;

  const float alpha = pal[0], beta = pbe[0];
  const float inv_gamma = 1.0f / pga[0];
  const float sa = alpha * 0.01f * inv_gamma;      // semantic scale folded
  const float sb = beta * inv_gamma;

  // A fragments (Q rows s0..s0+15), loaded once, shared by both GEMMs.
  const __hip_bfloat16* qrow = qb + ((size_t)bh * S_LEN + s0 + col) * D_DIM;
  s16x8 a0 = *reinterpret_cast<const s16x8*>(qrow + quad * 8);
  s16x8 a1 = *reinterpret_cast<const s16x8*>(qrow + 32 + quad * 8);

  const int t_base = wave * 256;
  uint32_t stg[16][2];                             // g~ packed bf16 pairs (32 regs)
  float    stk[16][4];                             // qk logits fp32 (64 regs)

  // ---- pass 1: pipelined sweep, depth-2 tiles + 1-iteration reg frags ----
  const char* cbase = (const char*)(cb + ((size_t)bh * S_LEN + t_base) * D_DIM);
  const char* kbase = (const char*)(kb + ((size_t)bh * S_LEN + t_base) * D_DIM);
  const int so0 = ((lane >> 3) << 7) | (((lane & 7) ^ ((lane >> 3) & 7)) << 4);

  auto stage_it = [&](int it) {
    unsigned short* db = &stage[wave][it & 3][0];
    const char* cs = cbase + it * 2048;
    const char* ks = kbase + it * 2048;
    __builtin_amdgcn_global_load_lds((gas_uint*)(cs + so0),        (las_uint*)(db),        16, 0, 0);
    __builtin_amdgcn_global_load_lds((gas_uint*)(cs + so0 + 1024), (las_uint*)(db + 512),  16, 0, 0);
    __builtin_amdgcn_global_load_lds((gas_uint*)(ks + so0),        (las_uint*)(db + 1024), 16, 0, 0);
    __builtin_amdgcn_global_load_lds((gas_uint*)(ks + so0 + 1024), (las_uint*)(db + 1536), 16, 0, 0);
  };

  const int xswz = (col & 7) << 4;                 // read-side swizzle (row = col)
  const int rb = col * 128;

  s16x8 cF0[2], cF1[2], kF0[2], kF1[2];            // even/odd fragment slots

  stage_it(0);
  stage_it(1);
  stage_it(2);                                     // 12 loads in flight
  asm volatile("s_waitcnt vmcnt(8)" ::: "memory"); // tile 0 landed
  {
    const char* cw = (const char*)&stage[wave][0][0];
    const char* kw = cw + 2048;
    cF0[0] = *reinterpret_cast<const s16x8*>(cw + rb + ((quad * 16) ^ xswz));
    cF1[0] = *reinterpret_cast<const s16x8*>(cw + rb + ((64 + quad * 16) ^ xswz));
    kF0[0] = *reinterpret_cast<const s16x8*>(kw + rb + ((quad * 16) ^ xswz));
    kF1[0] = *reinterpret_cast<const s16x8*>(kw + rb + ((64 + quad * 16) ^ xswz));
  }

  float lg[4] = {0.f, 0.f, 0.f, 0.f};
#pragma unroll
  for (int it = 0; it < 16; ++it) {
    if (it + 3 < 16) stage_it(it + 3);             // buf (it-1)&3: reads drained
    if (it < 13)       asm volatile("s_waitcnt vmcnt(8)" ::: "memory");
    else if (it == 13) asm volatile("s_waitcnt vmcnt(4)" ::: "memory");
    else if (it == 14) asm volatile("s_waitcnt vmcnt(0)" ::: "memory");
    if (it < 15) {                                 // prefetch frags(it+1)
      const char* cw = (const char*)&stage[wave][(it + 1) & 3][0];
      const char* kw = cw + 2048;
      const int sl = (it + 1) & 1;                 // compile-time under unroll
      cF0[sl] = *reinterpret_cast<const s16x8*>(cw + rb + ((quad * 16) ^ xswz));
      cF1[sl] = *reinterpret_cast<const s16x8*>(cw + rb + ((64 + quad * 16) ^ xswz));
      kF0[sl] = *reinterpret_cast<const s16x8*>(kw + rb + ((quad * 16) ^ xswz));
      kF1[sl] = *reinterpret_cast<const s16x8*>(kw + rb + ((64 + quad * 16) ^ xswz));
    }
    const int cur = it & 1;
    f32x4 dg = {0.f, 0.f, 0.f, 0.f};
    f32x4 dk = {0.f, 0.f, 0.f, 0.f};
    __builtin_amdgcn_s_setprio(1);
    dg = __builtin_amdgcn_mfma_f32_16x16x32_bf16(a0, cF0[cur], dg, 0, 0, 0);
    dg = __builtin_amdgcn_mfma_f32_16x16x32_bf16(a1, cF1[cur], dg, 0, 0, 0);
    dk = __builtin_amdgcn_mfma_f32_16x16x32_bf16(a0, kF0[cur], dk, 0, 0, 0);
    dk = __builtin_amdgcn_mfma_f32_16x16x32_bf16(a1, kF1[cur], dk, 0, 0, 0);
    __builtin_amdgcn_s_setprio(0);
    uint32_t p0 = 0, p1 = 0;
#pragma unroll
    for (int i = 0; i < 4; ++i) {
      float gv = __expf(dg[i] * 0.125f);           // /sqrt(D)
      unsigned short u = f2bf(gv);
      lg[i] += bf2f(u);                            // sum the ROUNDED value (consistent)
      if (i < 2) p0 |= (uint32_t)u << (16 * i);
      else       p1 |= (uint32_t)u << (16 * (i - 2));
      stk[it][i] = dk[i];
    }
    stg[it][0] = p0;
    stg[it][1] = p1;
  }
#pragma unroll
  for (int m = 1; m < 16; m <<= 1) {
#pragma unroll
    for (int i = 0; i < 4; ++i) lg[i] += __shfl_xor(lg[i], m);
  }
  if (col == 0) {
#pragma unroll
    for (int i = 0; i < 4; ++i) red0[wave][quad * 4 + i] = lg[i];
  }
  __syncthreads();
  float ilg[4];
#pragma unroll
  for (int i = 0; i < 4; ++i) {
    int rr = quad * 4 + i;
    ilg[i] = 1.0f / (red0[0][rr] + red0[1][rr] + red0[2][rr] + red0[3][rr]);
  }

  // ---- pass 2 (register-only): combine + l_w ----
  float lw[4] = {0.f, 0.f, 0.f, 0.f};
#pragma unroll
  for (int it = 0; it < 16; ++it) {
#pragma unroll
    for (int i = 0; i < 4; ++i) {
      unsigned short u = (unsigned short)((i < 2 ? stg[it][0] >> (16 * i)
                                                 : stg[it][1] >> (16 * (i - 2))) & 0xffffu);
      float gv = bf2f(u) * ilg[i];
      float z = sa * stk[it][i] + sb * gv;
      float wv = __expf(z);
      stk[it][i] = wv;
      lw[i] += wv;
    }
  }
#pragma unroll
  for (int m = 1; m < 16; m <<= 1) {
#pragma unroll
    for (int i = 0; i < 4; ++i) lw[i] += __shfl_xor(lw[i], m);
  }
  if (col == 0) {
#pragma unroll
    for (int i = 0; i < 4; ++i) red1[wave][quad * 4 + i] = lw[i];
  }
  __syncthreads();
  float ilw[4];
#pragma unroll
  for (int i = 0; i < 4; ++i) {
    int rr = quad * 4 + i;
    ilw[i] = 1.0f / (red1[0][rr] + red1[1][rr] + red1[2][rr] + red1[3][rr]);
  }

  // ---- pass 3: normalize + write wt (t, s) layout ----
  __hip_bfloat16* wrow = wt + ((size_t)bh * S_LEN + t_base + col) * S_LEN + s0 + quad * 4;
#pragma unroll
  for (int it = 0; it < 16; ++it) {
    us4 o;
#pragma unroll
    for (int i = 0; i < 4; ++i) o[i] = f2bf(stk[it][i] * ilw[i]);
    *reinterpret_cast<us4*>(wrow + (size_t)it * 16 * S_LEN) = o;
  }
}

// ---------------------------------------------------------------------------
// K4 v3: 256x256 tile, 512 thr (8 waves, 2Mx4N -> 128x64/wave), BK=32,
// FOUR rotating LDS buffers (4 x 32 KB = 128 KB) -> stage target (kt+2)&3
// never aliases a buffer being read (kt&3 / (kt+1)&3): deep lookahead with
// NO overwrite hazard. Per K-tile: 2 phases x {8 ds_read_b128, issue 2
// gloads of tile kt+2 (A@p0, B@p1), barrier, lgkmcnt(0), setprio, 16 MFMA,
// setprio, barrier}; transition vmcnt(4) (tile kt+2 in flight - never
// drains until kt=30 tail). 64-B rows -> swizzle: physical slot =
// quad ^ ((row>>1)&3) (2-way = free), inverse on gload source (rule 21).
// Accumulation order over s unchanged -> bit-identical output.
// ---------------------------------------------------------------------------
__global__ __launch_bounds__(512) void k_outgemm(const __hip_bfloat16* __restrict__ wt,
                                                 const __hip_bfloat16* __restrict__ tT,
                                                 float* __restrict__ out) {
  __shared__ __hip_bfloat16 As[4][256 * 32];       // 4 x 16 KB
  __shared__ __hip_bfloat16 Bs[4][256 * 32];       // 4 x 16 KB -> 128 KB total
  const int tid = threadIdx.x;
  const int wave = tid >> 6, lane = tid & 63;
  const int quad = lane >> 4, col = lane & 15;

  const int g = blockIdx.x;                        // 0..255 (1 block/CU)
  const int xcd = g & 7;
  const int local = g >> 3;                        // 0..31
  const int bh = xcd * 4 + (local >> 3);           // 4 bh per XCD
  const int tile = local & 7;
  const int m0 = (tile >> 1) * 256;                // t
  const int n0 = (tile & 1) * 256;                 // e
  const int b = bh >> 3;

  const __hip_bfloat16* Ag = wt + (size_t)bh * S_LEN * S_LEN;   // [t][s], stride S
  const __hip_bfloat16* Bg = tT + (size_t)b * E_DIM * S_LEN;    // [e][s], stride S

  const int mw = (wave >> 2) * 128;                // wave M offset
  const int nw = (wave & 3) * 64;                  // wave N offset

  // staging: row R = j*128 + wave*16 + (lane>>2); (R>>1)&3 == (lane>>3)&3
  const int scol  = ((lane & 3) ^ ((lane >> 3) & 3)) * 8;   // inverse-swz src col (elems)
  // read: row = (16-mult) + col; (row>>1)&3 == (col>>1)&3
  const int sslot = (quad ^ ((col >> 1) & 3)) * 16;         // physical slot byte in 64-B row

  f32x4 acc[8][4];
#pragma unroll
  for (int i = 0; i < 8; ++i)
#pragma unroll
    for (int j = 0; j < 4; ++j) acc[i][j] = (f32x4){0.f, 0.f, 0.f, 0.f};

  auto stageA = [&](int kt) {                      // 2 gloads (16 KB: 256 rows x 64 B)
    const int k0 = kt * 32;
    __hip_bfloat16* L = &As[kt & 3][0];
#pragma unroll
    for (int j = 0; j < 2; ++j) {
      const int R = j * 128 + wave * 16 + (lane >> 2);
      const __hip_bfloat16* gp = Ag + (size_t)(m0 + R) * S_LEN + k0 + scol;
      __builtin_amdgcn_global_load_lds((gas_uint*)gp,
                                       (las_uint*)(L + (j * 128 + wave * 16) * 32), 16, 0, 0);
    }
  };
  auto stageB = [&](int kt) {
    const int k0 = kt * 32;
    __hip_bfloat16* L = &Bs[kt & 3][0];
#pragma unroll
    for (int j = 0; j < 2; ++j) {
      const int R = j * 128 + wave * 16 + (lane >> 2);
      const __hip_bfloat16* gp = Bg + (size_t)(n0 + R) * S_LEN + k0 + scol;
      __builtin_amdgcn_global_load_lds((gas_uint*)gp,
                                       (las_uint*)(L + (j * 128 + wave * 16) * 32), 16, 0, 0);
    }
  };

  // prologue: tiles 0 and 1 staged (8 gloads); wait tile 0 (tile 1 in flight)
  stageA(0); stageB(0); stageA(1); stageB(1);
  asm volatile("s_waitcnt vmcnt(4)" ::: "memory");
  __builtin_amdgcn_s_barrier();

#pragma unroll 1
  for (int kt = 0; kt < 32; ++kt) {
    const char* Ab = (const char*)&As[kt & 3][0];
    const char* Bb = (const char*)&Bs[kt & 3][0];
#pragma unroll
    for (int p = 0; p < 2; ++p) {                  // phase p: m-half mh = p
      s16x8 af[4], bfr[4];
#pragma unroll
      for (int i = 0; i < 4; ++i) {
        const int row = mw + (p * 4 + i) * 16 + col;
        af[i] = *reinterpret_cast<const s16x8*>(Ab + row * 64 + sslot);
      }
#pragma unroll
      for (int i = 0; i < 4; ++i) {
        const int row = nw + i * 16 + col;
        bfr[i] = *reinterpret_cast<const s16x8*>(Bb + row * 64 + sslot);
      }
      if (kt + 2 < 32) {                           // lookahead-2: buf (kt+2)&3 is idle
        if (p == 0) stageA(kt + 2);
        else        stageB(kt + 2);
      }
      __builtin_amdgcn_s_barrier();
      asm volatile("s_waitcnt lgkmcnt(0)" ::: "memory");
      __builtin_amdgcn_s_setprio(1);
#pragma unroll
      for (int mi = 0; mi < 4; ++mi)
#pragma unroll
        for (int ni = 0; ni < 4; ++ni)
          acc[p * 4 + mi][ni] = __builtin_amdgcn_mfma_f32_16x16x32_bf16(
              af[mi], bfr[ni], acc[p * 4 + mi][ni], 0, 0, 0);
      __builtin_amdgcn_s_setprio(0);
      if (p == 1) {                                // transition: tile kt+1 landed,
        if (kt < 30)       asm volatile("s_waitcnt vmcnt(4)" ::: "memory"); // kt+2 in flight
        else if (kt == 30) asm volatile("s_waitcnt vmcnt(0)" ::: "memory"); // tail drain
      }
      __builtin_amdgcn_s_barrier();
    }
  }

  // epilogue: C row = quad*4+reg (m), col = lane&15 (n)
#pragma unroll
  for (int mf = 0; mf < 8; ++mf)
#pragma unroll
    for (int nf = 0; nf < 4; ++nf)
#pragma unroll
      for (int i = 0; i < 4; ++i) {
        int m = m0 + mw + mf * 16 + quad * 4 + i;
        int n = n0 + nw + nf * 16 + col;
        out[((size_t)bh * S_LEN + m) * E_DIM + n] = acc[mf][nf][i];
      }
}

// ---------------------------------------------------------------------------
// Workspace layout (bytes):
//   qb  [0,   4M)   (BH,S,D) bf16
//   kb  [4M,  8M)
//   cb  [8M, 12M)
//   tT  [12M,16M)   (B,E,S) bf16
//   wt  [16M,80M)   (BH,S_t,S_s) bf16
// ---------------------------------------------------------------------------
extern "C" void kernel_launch(void* const* d_in, const int* in_sizes, int n_in,
                              void* d_out, int out_size, void* d_ws, size_t ws_size,
                              hipStream_t stream) {
  (void)in_sizes; (void)n_in; (void)out_size; (void)ws_size;
  const float* src = (const float*)d_in[0];
  const float* tgt = (const float*)d_in[1];
  const float* enc = (const float*)d_in[2];
  const float* pal = (const float*)d_in[3];
  const float* pbe = (const float*)d_in[4];
  const float* pga = (const float*)d_in[5];
  float* out = (float*)d_out;

  char* ws = (char*)d_ws;
  __hip_bfloat16* qb = (__hip_bfloat16*)(ws);
  __hip_bfloat16* kb = (__hip_bfloat16*)(ws + ((size_t)4 << 20));
  __hip_bfloat16* cb = (__hip_bfloat16*)(ws + ((size_t)8 << 20));
  __hip_bfloat16* tT = (__hip_bfloat16*)(ws + ((size_t)12 << 20));
  __hip_bfloat16* wt = (__hip_bfloat16*)(ws + ((size_t)16 << 20));

  // Fused prep: recurrence (blocks 0..7) + pack + transpose
  k_prep<<<NB_RECUR + NB_PACK + NB_TR, 256, 0, stream>>>(src, tgt, enc, qb, kb, cb, tT);
  // K3: weights (v7: depth-2 tiles + reg fragment pipeline)
  k_weights<<<dim3((S_LEN / 16) * BH_NUM), 256, 0, stream>>>(qb, kb, cb, wt, pal, pbe, pga);
  // K4 v3: 256^2 phase-split GEMM, 256 blocks x 512 thr
  k_outgemm<<<dim3(256), 512, 0, stream>>>(wt, tT, out);
}

// Round 13
// 201.335 us; speedup vs baseline: 1.1330x; 1.0045x over previous
//
#include <hip/hip_runtime.h>
#include <hip/hip_bf16.h>
#include <stdint.h>

// Problem constants: B=4, S=1024, E=512, H=8, D=64
#define S_LEN 1024
#define E_DIM 512
#define H_NUM 8
#define D_DIM 64
#define B_NUM 4
#define BH_NUM 32

using s16x8 = __attribute__((ext_vector_type(8))) short;           // 8 bf16 (4 VGPRs)
using f32x4 = __attribute__((ext_vector_type(4))) float;           // MFMA accumulator
using us4   = __attribute__((ext_vector_type(4))) unsigned short;  // 4 bf16 (8 B)

typedef const __attribute__((address_space(1))) uint32_t gas_uint;
typedef __attribute__((address_space(3))) uint32_t las_uint;

static __device__ __forceinline__ unsigned short f2bf(float f) {
  __hip_bfloat16 h = __float2bfloat16(f);
  return __builtin_bit_cast(unsigned short, h);
}
static __device__ __forceinline__ float bf2f(unsigned short u) {
  return __bfloat162float(__builtin_bit_cast(__hip_bfloat16, u));
}

// ---------------------------------------------------------------------------
// K_PREP: fused recurrence + pack + transpose (block-range dispatch).
// (original recurrence - behind every 202-204 us result; prep not chain-bound)
// ---------------------------------------------------------------------------
#define NB_RECUR 8
#define NB_PACK  2048
#define NB_TR    512

__global__ __launch_bounds__(256) void k_prep(const float* __restrict__ src,
                                              const float* __restrict__ tgt,
                                              const float* __restrict__ enc,
                                              __hip_bfloat16* __restrict__ qb,
                                              __hip_bfloat16* __restrict__ kb,
                                              __hip_bfloat16* __restrict__ cb,
                                              __hip_bfloat16* __restrict__ tT) {
  __shared__ float tile[64][65];                   // used by transpose branch only
  const int bid = blockIdx.x;
  const int tid = threadIdx.x;

  if (bid < NB_RECUR) {
    // ---- serial recurrence: c_t = tanh(cc*pe); cc' = k_t*c_t; cc_0 = k_0 ----
    int g = bid * 256 + tid;                       // 0..2047
    int d = g & 63;
    int bh = g >> 6;
    int h = bh & 7;
    int b = bh >> 3;
    float pe = enc[h * D_DIM + d];
    float pe2 = 2.0f * pe;                         // tanh(x)=sgn(x)(1-e)/(1+e), e=exp(-2|x|)
    const float* tp = tgt + (size_t)b * S_LEN * E_DIM + h * D_DIM + d;
    __hip_bfloat16* cp = cb + (size_t)bh * S_LEN * D_DIM + d;

    constexpr int CH = 32;                         // prefetch chunk (registers)
    float bufA[CH], bufB[CH];
#pragma unroll
    for (int i = 0; i < CH; ++i) bufA[i] = tp[(size_t)i * E_DIM];
    float cc = bufA[0];                            // carry_0 = k_0

#pragma unroll 1
    for (int ch = 0; ch < S_LEN / CH; ch += 2) {
      if (ch + 1 < S_LEN / CH) {
#pragma unroll
        for (int i = 0; i < CH; ++i)
          bufB[i] = tp[(size_t)((ch + 1) * CH + i) * E_DIM];
      }
#pragma unroll
      for (int i = 0; i < CH; ++i) {
        float m = cc * pe2;
        float e = __expf(-fabsf(m));               // abs/neg fold to input mods
        float th = __builtin_copysignf((1.0f - e) * __builtin_amdgcn_rcpf(1.0f + e), m);
        cp[(size_t)(ch * CH + i) * D_DIM] = __float2bfloat16(th);
        cc = bufA[i] * th;
      }
      if (ch + 2 < S_LEN / CH) {
#pragma unroll
        for (int i = 0; i < CH; ++i)
          bufA[i] = tp[(size_t)((ch + 2) * CH + i) * E_DIM];
      }
#pragma unroll
      for (int i = 0; i < CH; ++i) {
        float m = cc * pe2;
        float e = __expf(-fabsf(m));
        float th = __builtin_copysignf((1.0f - e) * __builtin_amdgcn_rcpf(1.0f + e), m);
        cp[(size_t)((ch + 1) * CH + i) * D_DIM] = __float2bfloat16(th);
        cc = bufB[i] * th;
      }
    }
  } else if (bid < NB_RECUR + NB_PACK) {
    // ---- pack src/tgt (b,s,e) fp32 -> (bh,s,d) bf16, 4 elts/thread ----
    size_t i4 = ((size_t)(bid - NB_RECUR) * 256 + tid) * 4;   // < 2M
    float4 s4 = *reinterpret_cast<const float4*>(src + i4);
    float4 t4 = *reinterpret_cast<const float4*>(tgt + i4);
    int e = (int)(i4 & 511);                       // e%4==0, within one head (D=64)
    size_t bs = i4 >> 9;
    int s = (int)(bs & 1023);
    int b = (int)(bs >> 10);
    int h = e >> 6, d = e & 63;
    size_t o = (((size_t)(b * H_NUM + h) * S_LEN) + s) * D_DIM + d;
    us4 qv = {f2bf(s4.x), f2bf(s4.y), f2bf(s4.z), f2bf(s4.w)};
    us4 kv = {f2bf(t4.x), f2bf(t4.y), f2bf(t4.z), f2bf(t4.w)};
    *reinterpret_cast<us4*>(qb + o) = qv;
    *reinterpret_cast<us4*>(kb + o) = kv;
  } else {
    // ---- transpose tgt (b,s,e) -> tT (b,e,s) bf16, 64x64 tiles ----
    int lb = bid - (NB_RECUR + NB_PACK);           // 0..511
    int sx = lb & 15, ey = (lb >> 4) & 7, b = lb >> 7;
    int e0 = ey * 64, s0 = sx * 64;
    int tx = tid & 63, ty = tid >> 6;              // ty 0..3
    const float* p = tgt + ((size_t)b * S_LEN + s0) * E_DIM + e0;
#pragma unroll
    for (int r = ty; r < 64; r += 4) tile[r][tx] = p[(size_t)r * E_DIM + tx];
    __syncthreads();
    __hip_bfloat16* q = tT + ((size_t)b * E_DIM + e0) * S_LEN + s0;
#pragma unroll
    for (int r = ty; r < 64; r += 4) q[(size_t)r * S_LEN + tx] = __float2bfloat16(tile[tx][r]);
  }
}

// ---------------------------------------------------------------------------
// K3: attention weights (v7, proven ~50.3 us; kw closed).
// ---------------------------------------------------------------------------
__global__ __launch_bounds__(256) void k_weights(const __hip_bfloat16* __restrict__ qb,
                                                 const __hip_bfloat16* __restrict__ kb,
                                                 const __hip_bfloat16* __restrict__ cb,
                                                 __hip_bfloat16* __restrict__ wt,
                                                 const float* __restrict__ pal,
                                                 const float* __restrict__ pbe,
                                                 const float* __restrict__ pga) {
  // [wave][buf][c: ushort 0..1023 | k: ushort 1024..2047]  => 64 KB
  __shared__ unsigned short stage[4][4][2048];
  __shared__ float red0[4][16];                    // per-wave l_g partials
  __shared__ float red1[4][16];                    // per-wave l_w partials

  const int tid = threadIdx.x;
  const int wave = tid >> 6, lane = tid & 63;
  const int quad = lane >> 4, col = lane & 15;

  // XCD-aware decode: xcd = g&7 (round-robin), r enumerates (bh-sub, s-tile)
  const int g = blockIdx.x;
  const int xcd = g & 7;
  const int r = g >> 3;                            // 0..255
  const int bh = xcd * 4 + (r >> 6);               // 4 bh per XCD
  const int s0 = (r & 63) * 16;

  const float alpha = pal[0], beta = pbe[0];
  const float inv_gamma = 1.0f / pga[0];
  const float sa = alpha * 0.01f * inv_gamma;      // semantic scale folded
  const float sb = beta * inv_gamma;

  // A fragments (Q rows s0..s0+15), loaded once, shared by both GEMMs.
  const __hip_bfloat16* qrow = qb + ((size_t)bh * S_LEN + s0 + col) * D_DIM;
  s16x8 a0 = *reinterpret_cast<const s16x8*>(qrow + quad * 8);
  s16x8 a1 = *reinterpret_cast<const s16x8*>(qrow + 32 + quad * 8);

  const int t_base = wave * 256;
  uint32_t stg[16][2];                             // g~ packed bf16 pairs (32 regs)
  float    stk[16][4];                             // qk logits fp32 (64 regs)

  // ---- pass 1: pipelined sweep, depth-2 tiles + 1-iteration reg frags ----
  const char* cbase = (const char*)(cb + ((size_t)bh * S_LEN + t_base) * D_DIM);
  const char* kbase = (const char*)(kb + ((size_t)bh * S_LEN + t_base) * D_DIM);
  const int so0 = ((lane >> 3) << 7) | (((lane & 7) ^ ((lane >> 3) & 7)) << 4);

  auto stage_it = [&](int it) {
    unsigned short* db = &stage[wave][it & 3][0];
    const char* cs = cbase + it * 2048;
    const char* ks = kbase + it * 2048;
    __builtin_amdgcn_global_load_lds((gas_uint*)(cs + so0),        (las_uint*)(db),        16, 0, 0);
    __builtin_amdgcn_global_load_lds((gas_uint*)(cs + so0 + 1024), (las_uint*)(db + 512),  16, 0, 0);
    __builtin_amdgcn_global_load_lds((gas_uint*)(ks + so0),        (las_uint*)(db + 1024), 16, 0, 0);
    __builtin_amdgcn_global_load_lds((gas_uint*)(ks + so0 + 1024), (las_uint*)(db + 1536), 16, 0, 0);
  };

  const int xswz = (col & 7) << 4;                 // read-side swizzle (row = col)
  const int rb = col * 128;

  s16x8 cF0[2], cF1[2], kF0[2], kF1[2];            // even/odd fragment slots

  stage_it(0);
  stage_it(1);
  stage_it(2);                                     // 12 loads in flight
  asm volatile("s_waitcnt vmcnt(8)" ::: "memory"); // tile 0 landed
  {
    const char* cw = (const char*)&stage[wave][0][0];
    const char* kw = cw + 2048;
    cF0[0] = *reinterpret_cast<const s16x8*>(cw + rb + ((quad * 16) ^ xswz));
    cF1[0] = *reinterpret_cast<const s16x8*>(cw + rb + ((64 + quad * 16) ^ xswz));
    kF0[0] = *reinterpret_cast<const s16x8*>(kw + rb + ((quad * 16) ^ xswz));
    kF1[0] = *reinterpret_cast<const s16x8*>(kw + rb + ((64 + quad * 16) ^ xswz));
  }

  float lg[4] = {0.f, 0.f, 0.f, 0.f};
#pragma unroll
  for (int it = 0; it < 16; ++it) {
    if (it + 3 < 16) stage_it(it + 3);             // buf (it-1)&3: reads drained
    if (it < 13)       asm volatile("s_waitcnt vmcnt(8)" ::: "memory");
    else if (it == 13) asm volatile("s_waitcnt vmcnt(4)" ::: "memory");
    else if (it == 14) asm volatile("s_waitcnt vmcnt(0)" ::: "memory");
    if (it < 15) {                                 // prefetch frags(it+1)
      const char* cw = (const char*)&stage[wave][(it + 1) & 3][0];
      const char* kw = cw + 2048;
      const int sl = (it + 1) & 1;                 // compile-time under unroll
      cF0[sl] = *reinterpret_cast<const s16x8*>(cw + rb + ((quad * 16) ^ xswz));
      cF1[sl] = *reinterpret_cast<const s16x8*>(cw + rb + ((64 + quad * 16) ^ xswz));
      kF0[sl] = *reinterpret_cast<const s16x8*>(kw + rb + ((quad * 16) ^ xswz));
      kF1[sl] = *reinterpret_cast<const s16x8*>(kw + rb + ((64 + quad * 16) ^ xswz));
    }
    const int cur = it & 1;
    f32x4 dg = {0.f, 0.f, 0.f, 0.f};
    f32x4 dk = {0.f, 0.f, 0.f, 0.f};
    __builtin_amdgcn_s_setprio(1);
    dg = __builtin_amdgcn_mfma_f32_16x16x32_bf16(a0, cF0[cur], dg, 0, 0, 0);
    dg = __builtin_amdgcn_mfma_f32_16x16x32_bf16(a1, cF1[cur], dg, 0, 0, 0);
    dk = __builtin_amdgcn_mfma_f32_16x16x32_bf16(a0, kF0[cur], dk, 0, 0, 0);
    dk = __builtin_amdgcn_mfma_f32_16x16x32_bf16(a1, kF1[cur], dk, 0, 0, 0);
    __builtin_amdgcn_s_setprio(0);
    uint32_t p0 = 0, p1 = 0;
#pragma unroll
    for (int i = 0; i < 4; ++i) {
      float gv = __expf(dg[i] * 0.125f);           // /sqrt(D)
      unsigned short u = f2bf(gv);
      lg[i] += bf2f(u);                            // sum the ROUNDED value (consistent)
      if (i < 2) p0 |= (uint32_t)u << (16 * i);
      else       p1 |= (uint32_t)u << (16 * (i - 2));
      stk[it][i] = dk[i];
    }
    stg[it][0] = p0;
    stg[it][1] = p1;
  }
#pragma unroll
  for (int m = 1; m < 16; m <<= 1) {
#pragma unroll
    for (int i = 0; i < 4; ++i) lg[i] += __shfl_xor(lg[i], m);
  }
  if (col == 0) {
#pragma unroll
    for (int i = 0; i < 4; ++i) red0[wave][quad * 4 + i] = lg[i];
  }
  __syncthreads();
  float ilg[4];
#pragma unroll
  for (int i = 0; i < 4; ++i) {
    int rr = quad * 4 + i;
    ilg[i] = 1.0f / (red0[0][rr] + red0[1][rr] + red0[2][rr] + red0[3][rr]);
  }

  // ---- pass 2 (register-only): combine + l_w ----
  float lw[4] = {0.f, 0.f, 0.f, 0.f};
#pragma unroll
  for (int it = 0; it < 16; ++it) {
#pragma unroll
    for (int i = 0; i < 4; ++i) {
      unsigned short u = (unsigned short)((i < 2 ? stg[it][0] >> (16 * i)
                                                 : stg[it][1] >> (16 * (i - 2))) & 0xffffu);
      float gv = bf2f(u) * ilg[i];
      float z = sa * stk[it][i] + sb * gv;
      float wv = __expf(z);
      stk[it][i] = wv;
      lw[i] += wv;
    }
  }
#pragma unroll
  for (int m = 1; m < 16; m <<= 1) {
#pragma unroll
    for (int i = 0; i < 4; ++i) lw[i] += __shfl_xor(lw[i], m);
  }
  if (col == 0) {
#pragma unroll
    for (int i = 0; i < 4; ++i) red1[wave][quad * 4 + i] = lw[i];
  }
  __syncthreads();
  float ilw[4];
#pragma unroll
  for (int i = 0; i < 4; ++i) {
    int rr = quad * 4 + i;
    ilw[i] = 1.0f / (red1[0][rr] + red1[1][rr] + red1[2][rr] + red1[3][rr]);
  }

  // ---- pass 3: normalize + write wt (t, s) layout ----
  __hip_bfloat16* wrow = wt + ((size_t)bh * S_LEN + t_base + col) * S_LEN + s0 + quad * 4;
#pragma unroll
  for (int it = 0; it < 16; ++it) {
    us4 o;
#pragma unroll
    for (int i = 0; i < 4; ++i) o[i] = f2bf(stk[it][i] * ilw[i]);
    *reinterpret_cast<us4*>(wrow + (size_t)it * 16 * S_LEN) = o;
  }
}

// ---------------------------------------------------------------------------
// K4 v4 = v3 with the sync structure thinned to ONE barrier per K-tile +
// lookahead-3 (m233 lesson: v3's 4 barriers + lgkmcnt(0)/tile kept the
// 2-phase lockstep; the counted-vmcnt lever needs loads spanning few sync
// points):
//   - safety: 4-buffer rotation; single end-of-tile barrier bounds wave
//     drift to <1 tile; stage target (kt+3)&3 == (kt-1)&3, a buffer all
//     waves finished BEFORE the previous barrier -> no overwrite hazard;
//   - visibility: per-wave vmcnt(8) before the barrier retires own kt+1
//     loads (only kt+2,kt+3 = 8 stay in flight) -> post-barrier all waves'
//     kt+1 data in LDS; sched_barrier(0) after s_barrier stops ds_read
//     hoisting above it (rule 18);
//   - no manual lgkmcnt: compiler emits precise counts for ds_read->MFMA
//     and can pipeline the whole tile body;
//   - B-fragments read once per tile (identical in both halves of v3).
// Barriers 128 -> 31. Same swizzle/accumulation order -> bit-identical out.
// ---------------------------------------------------------------------------
__global__ __launch_bounds__(512) void k_outgemm(const __hip_bfloat16* __restrict__ wt,
                                                 const __hip_bfloat16* __restrict__ tT,
                                                 float* __restrict__ out) {
  __shared__ __hip_bfloat16 As[4][256 * 32];       // 4 x 16 KB
  __shared__ __hip_bfloat16 Bs[4][256 * 32];       // 4 x 16 KB -> 128 KB total
  const int tid = threadIdx.x;
  const int wave = tid >> 6, lane = tid & 63;
  const int quad = lane >> 4, col = lane & 15;

  const int g = blockIdx.x;                        // 0..255 (1 block/CU)
  const int xcd = g & 7;
  const int local = g >> 3;                        // 0..31
  const int bh = xcd * 4 + (local >> 3);           // 4 bh per XCD
  const int tile = local & 7;
  const int m0 = (tile >> 1) * 256;                // t
  const int n0 = (tile & 1) * 256;                 // e
  const int b = bh >> 3;

  const __hip_bfloat16* Ag = wt + (size_t)bh * S_LEN * S_LEN;   // [t][s], stride S
  const __hip_bfloat16* Bg = tT + (size_t)b * E_DIM * S_LEN;    // [e][s], stride S

  const int mw = (wave >> 2) * 128;                // wave M offset
  const int nw = (wave & 3) * 64;                  // wave N offset

  // staging: row R = j*128 + wave*16 + (lane>>2); (R>>1)&3 == (lane>>3)&3
  const int scol  = ((lane & 3) ^ ((lane >> 3) & 3)) * 8;   // inverse-swz src col (elems)
  // read: row = (16-mult) + col; (row>>1)&3 == (col>>1)&3
  const int sslot = (quad ^ ((col >> 1) & 3)) * 16;         // physical slot byte in 64-B row

  f32x4 acc[8][4];
#pragma unroll
  for (int i = 0; i < 8; ++i)
#pragma unroll
    for (int j = 0; j < 4; ++j) acc[i][j] = (f32x4){0.f, 0.f, 0.f, 0.f};

  auto stageA = [&](int kt) {                      // 2 gloads/wave (16 KB tile)
    const int k0 = kt * 32;
    __hip_bfloat16* L = &As[kt & 3][0];
#pragma unroll
    for (int j = 0; j < 2; ++j) {
      const int R = j * 128 + wave * 16 + (lane >> 2);
      const __hip_bfloat16* gp = Ag + (size_t)(m0 + R) * S_LEN + k0 + scol;
      __builtin_amdgcn_global_load_lds((gas_uint*)gp,
                                       (las_uint*)(L + (j * 128 + wave * 16) * 32), 16, 0, 0);
    }
  };
  auto stageB = [&](int kt) {
    const int k0 = kt * 32;
    __hip_bfloat16* L = &Bs[kt & 3][0];
#pragma unroll
    for (int j = 0; j < 2; ++j) {
      const int R = j * 128 + wave * 16 + (lane >> 2);
      const __hip_bfloat16* gp = Bg + (size_t)(n0 + R) * S_LEN + k0 + scol;
      __builtin_amdgcn_global_load_lds((gas_uint*)gp,
                                       (las_uint*)(L + (j * 128 + wave * 16) * 32), 16, 0, 0);
    }
  };

  // prologue: tiles 0..2 staged (12 gloads/wave); wait tile 0 (1,2 in flight)
  stageA(0); stageB(0); stageA(1); stageB(1); stageA(2); stageB(2);
  asm volatile("s_waitcnt vmcnt(8)" ::: "memory");
  __builtin_amdgcn_s_barrier();
  __builtin_amdgcn_sched_barrier(0);

#pragma unroll 1
  for (int kt = 0; kt < 32; ++kt) {
    const char* Ab = (const char*)&As[kt & 3][0];
    const char* Bb = (const char*)&Bs[kt & 3][0];

    s16x8 bfr[4];                                  // B frags: same for both halves
#pragma unroll
    for (int i = 0; i < 4; ++i) {
      const int row = nw + i * 16 + col;
      bfr[i] = *reinterpret_cast<const s16x8*>(Bb + row * 64 + sslot);
    }
    s16x8 af0[4];
#pragma unroll
    for (int i = 0; i < 4; ++i) {
      const int row = mw + i * 16 + col;
      af0[i] = *reinterpret_cast<const s16x8*>(Ab + row * 64 + sslot);
    }
    if (kt + 3 < 32) stageA(kt + 3);               // buf (kt+3)&3 == (kt-1)&3: idle
    __builtin_amdgcn_s_setprio(1);
#pragma unroll
    for (int mi = 0; mi < 4; ++mi)
#pragma unroll
      for (int ni = 0; ni < 4; ++ni)
        acc[mi][ni] = __builtin_amdgcn_mfma_f32_16x16x32_bf16(af0[mi], bfr[ni], acc[mi][ni], 0, 0, 0);
    __builtin_amdgcn_s_setprio(0);

    s16x8 af1[4];
#pragma unroll
    for (int i = 0; i < 4; ++i) {
      const int row = mw + (4 + i) * 16 + col;
      af1[i] = *reinterpret_cast<const s16x8*>(Ab + row * 64 + sslot);
    }
    if (kt + 3 < 32) stageB(kt + 3);
    __builtin_amdgcn_s_setprio(1);
#pragma unroll
    for (int mi = 0; mi < 4; ++mi)
#pragma unroll
      for (int ni = 0; ni < 4; ++ni)
        acc[4 + mi][ni] = __builtin_amdgcn_mfma_f32_16x16x32_bf16(af1[mi], bfr[ni], acc[4 + mi][ni], 0, 0, 0);
    __builtin_amdgcn_s_setprio(0);

    if (kt < 31) {                                 // end-of-tile: kt+1 landed,
      if (kt <= 28)      asm volatile("s_waitcnt vmcnt(8)" ::: "memory"); // kt+2,kt+3 fly
      else if (kt == 29) asm volatile("s_waitcnt vmcnt(4)" ::: "memory");
      else               asm volatile("s_waitcnt vmcnt(0)" ::: "memory");
      __builtin_amdgcn_s_barrier();
      __builtin_amdgcn_sched_barrier(0);           // no ds_read hoists above (rule 18)
    }
  }

  // epilogue: C row = quad*4+reg (m), col = lane&15 (n)
#pragma unroll
  for (int mf = 0; mf < 8; ++mf)
#pragma unroll
    for (int nf = 0; nf < 4; ++nf)
#pragma unroll
      for (int i = 0; i < 4; ++i) {
        int m = m0 + mw + mf * 16 + quad * 4 + i;
        int n = n0 + nw + nf * 16 + col;
        out[((size_t)bh * S_LEN + m) * E_DIM + n] = acc[mf][nf][i];
      }
}

// ---------------------------------------------------------------------------
// Workspace layout (bytes):
//   qb  [0,   4M)   (BH,S,D) bf16
//   kb  [4M,  8M)
//   cb  [8M, 12M)
//   tT  [12M,16M)   (B,E,S) bf16
//   wt  [16M,80M)   (BH,S_t,S_s) bf16
// ---------------------------------------------------------------------------
extern "C" void kernel_launch(void* const* d_in, const int* in_sizes, int n_in,
                              void* d_out, int out_size, void* d_ws, size_t ws_size,
                              hipStream_t stream) {
  (void)in_sizes; (void)n_in; (void)out_size; (void)ws_size;
  const float* src = (const float*)d_in[0];
  const float* tgt = (const float*)d_in[1];
  const float* enc = (const float*)d_in[2];
  const float* pal = (const float*)d_in[3];
  const float* pbe = (const float*)d_in[4];
  const float* pga = (const float*)d_in[5];
  float* out = (float*)d_out;

  char* ws = (char*)d_ws;
  __hip_bfloat16* qb = (__hip_bfloat16*)(ws);
  __hip_bfloat16* kb = (__hip_bfloat16*)(ws + ((size_t)4 << 20));
  __hip_bfloat16* cb = (__hip_bfloat16*)(ws + ((size_t)8 << 20));
  __hip_bfloat16* tT = (__hip_bfloat16*)(ws + ((size_t)12 << 20));
  __hip_bfloat16* wt = (__hip_bfloat16*)(ws + ((size_t)16 << 20));

  // Fused prep: recurrence (blocks 0..7) + pack + transpose
  k_prep<<<NB_RECUR + NB_PACK + NB_TR, 256, 0, stream>>>(src, tgt, enc, qb, kb, cb, tT);
  // K3: weights (v7: depth-2 tiles + reg fragment pipeline)
  k_weights<<<dim3((S_LEN / 16) * BH_NUM), 256, 0, stream>>>(qb, kb, cb, wt, pal, pbe, pga);
  // K4 v4: 256^2 GEMM, 1 barrier/K-tile, lookahead-3
  k_outgemm<<<dim3(256), 512, 0, stream>>>(wt, tT, out);
}